// Round 4
// baseline (61434.656 us; speedup 1.0000x reference)
//
#include <hip/hip_runtime.h>

#define T_STEPS 16384
#define N 2048
#define NBLK 256          // one block per CU
#define THREADS 256
#define NSLOT 4           // g ring slots; safe since blocks stay within 1 step

typedef unsigned long long u64;

// ---------------------------------------------------------------------------
// Protocol: publish p = g entering step p, in slots[p&3][j] as an 8B pair
//   (low 32: g bits, high 32: tag = p+1). The 8B aligned store is naturally
//   atomic, so tag fresh <=> g fresh -- flag and data in ONE coherent round
//   trip (old design needed publish->drain->flag->poll->load = two).
// Lockstep: reading publish t requires ALL blocks published t, which required
//   them to finish t-1 => max skew 1 step => overwriting publish t-3 is safe.
// Tags are monotonic 1..T+1; 0xAA poison / zeros never match a target.
// ---------------------------------------------------------------------------

__global__ void __launch_bounds__(THREADS, 1)
lif_kernel(const float* __restrict__ x_in, const float* __restrict__ w,
           const float* __restrict__ E_L, const float* __restrict__ tau_m,
           const float* __restrict__ R_I, const float* __restrict__ tau_g,
           const float* __restrict__ v0,  const float* __restrict__ g0,
           float* __restrict__ out, u64* __restrict__ slots)
{
    __shared__ float w_lds[8][N];     // 64 KB: one-time coalesced staging of w
    __shared__ float g_lds[2][N];     // 16 KB: double-buffered g image

    const int tid = threadIdx.x;
    const int blk = blockIdx.x;
    const int j0  = blk * 8;

    // ---- one-time: stage this block's 8 w-columns (transposed, diag=0) ----
    for (int r8 = 0; r8 < 8; ++r8) {
        int i = r8 * THREADS + tid;
        const float4* wrow = reinterpret_cast<const float4*>(w + (size_t)i * N + j0);
        float4 a = wrow[0], b = wrow[1];
        float vals[8] = {a.x, a.y, a.z, a.w, b.x, b.y, b.z, b.w};
        #pragma unroll
        for (int jc = 0; jc < 8; ++jc)
            w_lds[jc][i] = (i == j0 + jc) ? 0.0f : vals[jc];
    }
    __syncthreads();

    const int wv = tid >> 6;          // wave 0..3 (each owns 2 columns)
    const int ln = tid & 63;          // lane 0..63
    const int cA = 2 * wv;            // block-local column indices
    const int cB = 2 * wv + 1;

    // ---- one-time: w into registers. wreg[u] covers rows {r, r+1} of both
    //      columns, r = 2*ln + 128*u  (64 floats/lane) ----
    float4 wreg[16];
    #pragma unroll
    for (int u = 0; u < 16; ++u) {
        int r = 2 * ln + 128 * u;
        wreg[u].x = w_lds[cA][r];  wreg[u].y = w_lds[cA][r + 1];
        wreg[u].z = w_lds[cB][r];  wreg[u].w = w_lds[cB][r + 1];
    }

    // owner lanes: ln==0 -> col j0+cA, ln==32 -> col j0+cB
    const bool own  = (ln == 0) || (ln == 32);
    const int  jown = j0 + ((ln == 0) ? cA : cB);

    float v_st = 0.f, g_st = 0.f, eL = 0.f, tm = 1.f, ri = 0.f, tg = 1.f, xv = 0.f;
    if (own) {
        v_st = v0[jown]; g_st = g0[jown];
        eL = E_L[jown]; tm = tau_m[jown]; ri = R_I[jown]; tg = tau_g[jown];
        xv = x_in[jown];                              // t=0 input
        __hip_atomic_store(&slots[jown],              // publish 0: slot 0, tag 1
                           ((u64)1u << 32) | (u64)__float_as_uint(g_st),
                           __ATOMIC_RELAXED, __HIP_MEMORY_SCOPE_AGENT);
    }

    for (int t = 0; t < T_STEPS; ++t) {
        // ---- poll own quarter of g-image: 8 pairs/lane, tag must be t+1 ----
        const u64* slot = slots + (size_t)(t & 3) * N;
        const unsigned tgt = (unsigned)(t + 1);
        float gp[8];
        for (;;) {
            bool ok = true;
            #pragma unroll
            for (int u = 0; u < 4; ++u) {
                int j = 512 * wv + 2 * ln + 128 * u;
                u64 p0 = __hip_atomic_load(&slot[j],     __ATOMIC_RELAXED,
                                           __HIP_MEMORY_SCOPE_AGENT);
                u64 p1 = __hip_atomic_load(&slot[j + 1], __ATOMIC_RELAXED,
                                           __HIP_MEMORY_SCOPE_AGENT);
                ok = ok && ((unsigned)(p0 >> 32) == tgt)
                        && ((unsigned)(p1 >> 32) == tgt);
                gp[2 * u]     = __uint_as_float((unsigned)p0);
                gp[2 * u + 1] = __uint_as_float((unsigned)p1);
            }
            if (__all(ok)) break;     // uniform: all lanes retry together
        }

        // ---- share quarter via LDS (double-buffered; 1 barrier/step) ----
        float* gl = g_lds[t & 1];
        #pragma unroll
        for (int u = 0; u < 4; ++u) {
            int j = 512 * wv + 2 * ln + 128 * u;
            *reinterpret_cast<float2*>(&gl[j]) = make_float2(gp[2*u], gp[2*u+1]);
        }
        __syncthreads();

        // ---- matvec: 2 columns/wave, 64 rows/lane, w in regs ----
        float accA = 0.f, accB = 0.f;
        #pragma unroll
        for (int u = 0; u < 16; ++u) {
            int r = 2 * ln + 128 * u;
            float2 g2 = *reinterpret_cast<const float2*>(&gl[r]);
            accA = fmaf(wreg[u].x, g2.x, fmaf(wreg[u].y, g2.y, accA));
            accB = fmaf(wreg[u].z, g2.x, fmaf(wreg[u].w, g2.y, accB));
        }
        #pragma unroll
        for (int m = 1; m <= 32; m <<= 1) {          // 64-lane butterfly
            accA += __shfl_xor(accA, m, 64);
            accB += __shfl_xor(accB, m, 64);
        }

        // ---- neuron update + publish (owner lanes; publish store FIRST) ----
        if (own) {
            float sum    = (ln == 0) ? accA : accB;
            float I      = fmaf(0.9f, xv, sum);
            float v_next = v_st + (eL - v_st + I * ri) / tm;
            float soft   = 1.0f / (1.0f + expf(30.0f - v_next)); // sigmoid(v-30)
            bool  spiked = v_next >= 30.0f;
            v_st = spiked ? eL : v_next;
            g_st = spiked ? 1.0f : (g_st - g_st / tg);
            __hip_atomic_store(&slots[(size_t)((t + 1) & 3) * N + jown],
                               ((u64)(unsigned)(t + 2) << 32) |
                               (u64)__float_as_uint(g_st),
                               __ATOMIC_RELAXED, __HIP_MEMORY_SCOPE_AGENT);
            out[(size_t)t * N + jown] = soft;         // off critical path
            if (t + 1 < T_STEPS) xv = x_in[(size_t)(t + 1) * N + jown];
        }
        // no trailing barrier: next step writes g_lds[(t+1)&1] (other buffer),
        // and a wave reaches step t+2 (same buffer) only after the t+1 barrier,
        // which every wave enters only after finishing its step-t reads.
    }
}

extern "C" void kernel_launch(void* const* d_in, const int* in_sizes, int n_in,
                              void* d_out, int out_size, void* d_ws, size_t ws_size,
                              hipStream_t stream) {
    const float* x_in  = (const float*)d_in[0];
    const float* w     = (const float*)d_in[1];
    const float* E_L   = (const float*)d_in[2];
    const float* tau_m = (const float*)d_in[3];
    const float* R_I   = (const float*)d_in[4];
    const float* tau_g = (const float*)d_in[5];
    const float* v0    = (const float*)d_in[6];
    const float* g0    = (const float*)d_in[7];
    float* out = (float*)d_out;

    u64* slots = (u64*)d_ws;   // 4 slots x 2048 pairs x 8B = 64 KB

    // Poison 0xAA never matches a tag, but the FIRST (non-poisoned) call might
    // see stale garbage: zero the slots for safety (tag 0 matches nothing).
    hipMemsetAsync(d_ws, 0, NSLOT * N * sizeof(u64), stream);

    void* args[] = {(void*)&x_in, (void*)&w, (void*)&E_L, (void*)&tau_m,
                    (void*)&R_I, (void*)&tau_g, (void*)&v0, (void*)&g0,
                    (void*)&out, (void*)&slots};
    hipLaunchCooperativeKernel((const void*)lif_kernel, dim3(NBLK), dim3(THREADS),
                               args, 0, stream);
}